// Round 7
// baseline (423.392 us; speedup 1.0000x reference)
//
#include <hip/hip_runtime.h>
#include <hip/hip_bf16.h>

#define N_ATOMS 100000
#define K_NBR   64
#define N_STRUCT 32
#define HID     128
#define N_EDGE  (N_ATOMS * K_NBR)        // 6,400,000
#define ATOMS_PB 64                      // atoms per edge block
#define EDGES_PB (ATOMS_PB * K_NBR)      // 4096
#define NBLK_EL ((N_ATOMS + ATOMS_PB - 1) / ATOMS_PB)   // 1563
#define NBLK_G  (N_ATOMS / 8)            // 12500 (exact)

typedef unsigned int uint;

#if __has_builtin(__builtin_amdgcn_exp2f)
#define EXP2(v) __builtin_amdgcn_exp2f(v)
#else
#define EXP2(v) __expf((v) * 0.69314718056f)
#endif

__device__ __forceinline__ uint bf_rne(float f) {        // fp32 -> bf16 bits (RNE)
    uint u = __float_as_uint(f);
    return (u + 0x7fffu + ((u >> 16) & 1u)) >> 16;
}
__device__ __forceinline__ float ubf_lo(uint u) { return __uint_as_float(u << 16); }
__device__ __forceinline__ float ubf_hi(uint u) { return __uint_as_float(u & 0xffff0000u); }

// ---------------------------------------------------------------------------
// Weight prep (1 block):
//   pw4[d] = {2log2e*W1[0,d], 2log2e*W1[1,d], 2log2e*W1[2,d], w2[d]}
//   gw4[d] = {4*w2*W1[0,d],   4*w2*W1[1,d],   4*w2*W1[2,d],   0}
// identities: ex = e^{2p} = exp2(x·pw); r = 1/(1+ex); t = 1-2r;
//             e = sumw2 - 2 sum w2 r; (1-t^2)/4 = r - r^2.
// ---------------------------------------------------------------------------
__global__ void prep_kernel(const float* __restrict__ W1, const float* __restrict__ w2,
                            float4* __restrict__ pw4, float4* __restrict__ gw4,
                            float* __restrict__ sumw2)
{
    const float L2E2 = 2.885390082f;     // 2*log2(e)
    int d = threadIdx.x;                 // 128 threads
    float w0 = W1[d], w1 = W1[HID + d], wc = W1[2 * HID + d], wv = w2[d];
    pw4[d] = make_float4(L2E2 * w0, L2E2 * w1, L2E2 * wc, wv);
    gw4[d] = make_float4(4.f * wv * w0, 4.f * wv * w1, 4.f * wv * wc, 0.f);
    float v = wv;
    for (int off = 32; off; off >>= 1) v += __shfl_down(v, off, 64);
    __shared__ float sw_[2];
    if ((threadIdx.x & 63) == 0) sw_[threadIdx.x >> 6] = v;
    __syncthreads();
    if (threadIdx.x == 0) sumw2[0] = sw_[0] + sw_[1];
}

// ---------------------------------------------------------------------------
// Edge kernel: block owns 64 atoms (4096 edges).
//  A1: LDS-transpose its 64x64 nidx tile (coalesced [K,N] reads).
//  A2: per edge -> gidx = mask ? -1 : nb*64+ps; zero gr8 at masked slots;
//      compact unmasked local ids into LDS list (block-local ticket).
//  B : dense MLP loop over ~2048-entry list; writes bf16x3 gr8; accumulates
//      fp32 first[n] (LDS atomics) and per-struct energy bins.
// ---------------------------------------------------------------------------
__global__ __launch_bounds__(256) void edge_local(
    const float* __restrict__ x, const int* __restrict__ mask,
    const int* __restrict__ nidx, const int* __restrict__ pos,
    const int* __restrict__ batch,
    const float4* __restrict__ pw4, const float4* __restrict__ gw4,
    const float* __restrict__ sumw2p,
    uint2* __restrict__ gr8, int* __restrict__ gidx,
    float4* __restrict__ first4, float* __restrict__ part)
{
    __shared__ int tile[64][65];                 // 16.6 KB
    __shared__ unsigned short list[EDGES_PB];    // 8 KB
    __shared__ float sfirst[ATOMS_PB][4];
    __shared__ float sp[N_STRUCT];
    __shared__ int   sbatch[ATOMS_PB];
    __shared__ int   lcnt;

    const int tid = threadIdx.x, lane = tid & 63, w = tid >> 6;
    const int n0 = blockIdx.x * ATOMS_PB;
    const int ebase = n0 * K_NBR;

    if (tid == 0) lcnt = 0;
    if (tid < N_STRUCT) sp[tid] = 0.f;
    if (tid < ATOMS_PB) {
        int n = n0 + tid;
        sbatch[tid] = (n < N_ATOMS) ? batch[n] : 0;
        sfirst[tid][0] = 0.f; sfirst[tid][1] = 0.f; sfirst[tid][2] = 0.f;
    }
    #pragma unroll
    for (int i = 0; i < 16; ++i) {               // coalesced read of nidx[K,N]
        int k = i * 4 + w, n = n0 + lane;
        tile[k][lane] = (n < N_ATOMS) ? nidx[k * N_ATOMS + n] : 0;
    }
    __syncthreads();

    #pragma unroll
    for (int p = 0; p < EDGES_PB / 256; ++p) {   // 16 passes, coalesced
        int le = p * 256 + tid;
        int nl = le >> 6, k = le & 63;
        bool valid = (n0 + nl) < N_ATOMS;
        int ei = ebase + le;
        int un = 0;
        if (valid) {
            int m = mask[ei];
            un = (m == 0);
            int g = -1;
            if (un) g = tile[k][nl] * 64 + pos[ei];     // conflict-free (pad 65)
            else    gr8[ei] = make_uint2(0u, 0u);       // gathered sources read 0
            gidx[ei] = g;
        }
        unsigned long long bal = __ballot(un);
        int wcnt = __popcll(bal);
        int pre  = __popcll(bal & ((1ull << lane) - 1ull));
        int wbase;
        if (lane == 0) wbase = atomicAdd(&lcnt, wcnt);  // block-local ticket
        wbase = __shfl(wbase, 0, 64);
        if (un) list[wbase + pre] = (unsigned short)le;
    }
    __syncthreads();

    const int L = lcnt;
    const float sumw2 = sumw2p[0];

    for (int i = tid; i < L; i += 256) {
        int le  = list[i];
        int eid = ebase + le;
        const float* xp = x + (size_t)eid * 3;
        float x0 = xp[0], x1 = xp[1], x2 = xp[2];
        float rsum = 0.f, g0 = 0.f, g1 = 0.f, g2 = 0.f;
        for (int d = 0; d < HID; d += 4) {
            float4 wa = pw4[d], wb = pw4[d + 1], wc = pw4[d + 2], wd = pw4[d + 3];
            float4 Ga = gw4[d], Gb = gw4[d + 1], Gc = gw4[d + 2], Gd = gw4[d + 3];
            float ea = EXP2(fmaf(x0, wa.x, fmaf(x1, wa.y, x2 * wa.z)));
            float eb = EXP2(fmaf(x0, wb.x, fmaf(x1, wb.y, x2 * wb.z)));
            float ec = EXP2(fmaf(x0, wc.x, fmaf(x1, wc.y, x2 * wc.z)));
            float ed = EXP2(fmaf(x0, wd.x, fmaf(x1, wd.y, x2 * wd.z)));
            float aa = ea + 1.f, ab = eb + 1.f, ac = ec + 1.f, ad = ed + 1.f;
            float pab = aa * ab, pcd = ac * ad;
            float q   = __builtin_amdgcn_rcpf(pab * pcd);     // one rcp per 4 d
            float qab = q * pcd, qcd = q * pab;
            float ra = qab * ab, rb = qab * aa, rc = qcd * ad, rd = qcd * ac;
            rsum = fmaf(wa.w, ra, rsum);
            rsum = fmaf(wb.w, rb, rsum);
            rsum = fmaf(wc.w, rc, rsum);
            rsum = fmaf(wd.w, rd, rsum);
            float sa = fmaf(-ra, ra, ra);                     // r-r^2 = (1-t^2)/4
            float sb = fmaf(-rb, rb, rb);
            float sc = fmaf(-rc, rc, rc);
            float sd = fmaf(-rd, rd, rd);
            g0 = fmaf(sa, Ga.x, g0); g1 = fmaf(sa, Ga.y, g1); g2 = fmaf(sa, Ga.z, g2);
            g0 = fmaf(sb, Gb.x, g0); g1 = fmaf(sb, Gb.y, g1); g2 = fmaf(sb, Gb.z, g2);
            g0 = fmaf(sc, Gc.x, g0); g1 = fmaf(sc, Gc.y, g1); g2 = fmaf(sc, Gc.z, g2);
            g0 = fmaf(sd, Gd.x, g0); g1 = fmaf(sd, Gd.y, g1); g2 = fmaf(sd, Gd.z, g2);
        }
        float e = fmaf(-2.f, rsum, sumw2);
        uint lo = bf_rne(g0) | (bf_rne(g1) << 16);
        uint hi = bf_rne(g2);
        gr8[eid] = make_uint2(lo, hi);
        int a = le >> 6;
        atomicAdd(&sp[sbatch[a]], e);
        atomicAdd(&sfirst[a][0], g0);
        atomicAdd(&sfirst[a][1], g1);
        atomicAdd(&sfirst[a][2], g2);
    }
    __syncthreads();

    if (tid < ATOMS_PB && (n0 + tid) < N_ATOMS)
        first4[n0 + tid] = make_float4(sfirst[tid][0], sfirst[tid][1],
                                       sfirst[tid][2], 0.f);
    if (tid < N_STRUCT) part[(size_t)tid * NBLK_EL + blockIdx.x] = sp[tid];
}

// ---------------------------------------------------------------------------
// Gather-only forces: wave = 2 atoms; lane = k. Reads gidx (coalesced) +
// first4; 8B random gathers from gr8; writes forces. Blocks 0..31 also
// reduce preds partials.
// ---------------------------------------------------------------------------
__global__ __launch_bounds__(256) void atom_gather(
    const uint2* __restrict__ gr8, const int* __restrict__ gidx,
    const float4* __restrict__ first4, const float* __restrict__ part,
    float* __restrict__ out)
{
    const int tid = threadIdx.x, lane = tid & 63, w = tid >> 6;
    const int nA = blockIdx.x * 8 + w * 2;        // 12500 blocks * 8 = 100000
    const int nB = nA + 1;

    int gA = gidx[nA * 64 + lane];                // coalesced
    int gB = gidx[nB * 64 + lane];
    uint2 bA = make_uint2(0u, 0u), bB = make_uint2(0u, 0u);
    if (gA >= 0) bA = gr8[gA];                    // aligned 8B random gather
    if (gB >= 0) bB = gr8[gB];

    float sA0 = ubf_lo(bA.x), sA1 = ubf_hi(bA.x), sA2 = ubf_lo(bA.y);
    float sB0 = ubf_lo(bB.x), sB1 = ubf_hi(bB.x), sB2 = ubf_lo(bB.y);

    for (int off = 32; off; off >>= 1) {
        sA0 += __shfl_down(sA0, off, 64);
        sA1 += __shfl_down(sA1, off, 64);
        sA2 += __shfl_down(sA2, off, 64);
        sB0 += __shfl_down(sB0, off, 64);
        sB1 += __shfl_down(sB1, off, 64);
        sB2 += __shfl_down(sB2, off, 64);
    }
    if (lane == 0) {
        float4 fA = first4[nA];
        float4 fB = first4[nB];
        float* fo = out + N_STRUCT + (size_t)nA * 3;
        fo[0] = fA.x - sA0; fo[1] = fA.y - sA1; fo[2] = fA.z - sA2;
        fo[3] = fB.x - sB0; fo[4] = fB.y - sB1; fo[5] = fB.z - sB2;
    }

    if (blockIdx.x < N_STRUCT) {                  // fused preds reduction
        int s = blockIdx.x;
        float v = 0.f;
        for (int i = tid; i < NBLK_EL; i += 256) v += part[(size_t)s * NBLK_EL + i];
        for (int off = 32; off; off >>= 1) v += __shfl_down(v, off, 64);
        __shared__ float sv[4];
        if (lane == 0) sv[w] = v;
        __syncthreads();
        if (tid == 0) out[s] = sv[0] + sv[1] + sv[2] + sv[3];
    }
}

// ---------------------------------------------------------------------------
extern "C" void kernel_launch(void* const* d_in, const int* in_sizes, int n_in,
                              void* d_out, int out_size, void* d_ws, size_t ws_size,
                              hipStream_t stream)
{
    const float* x    = (const float*)d_in[0];
    const int*   nidx = (const int*)d_in[1];   // [K, N]
    const int*   npos = (const int*)d_in[2];   // [N, K]
    const int*   mask = (const int*)d_in[3];   // [N, K]
    const int*   bidx = (const int*)d_in[4];   // [N]
    const float* W1   = (const float*)d_in[5]; // [3, HID]
    const float* w2   = (const float*)d_in[6]; // [HID]
    float* out = (float*)d_out;

    char* ws = (char*)d_ws;
    uint2*  gr8    = (uint2*)ws;                                    // 51.2 MB
    int*    gidx   = (int*)(ws + (size_t)N_EDGE * 8);               // 25.6 MB
    float4* first4 = (float4*)(ws + (size_t)N_EDGE * 12);           // 1.6 MB
    float*  part   = (float*)(ws + (size_t)N_EDGE * 12
                                 + (size_t)N_ATOMS * 16);           // 200 KB
    char*   tail   = ws + (size_t)N_EDGE * 12 + (size_t)N_ATOMS * 16
                        + (size_t)N_STRUCT * NBLK_EL * 4;
    float4* pw4   = (float4*)tail;                                  // 2 KB
    float4* gw4   = (float4*)(tail + HID * 16);                     // 2 KB
    float*  sumw2 = (float*)(tail + 2 * HID * 16);

    hipLaunchKernelGGL(prep_kernel, dim3(1), dim3(128), 0, stream,
                       W1, w2, pw4, gw4, sumw2);
    hipLaunchKernelGGL(edge_local, dim3(NBLK_EL), dim3(256), 0, stream,
                       x, mask, nidx, npos, bidx, pw4, gw4, sumw2,
                       gr8, gidx, first4, part);
    hipLaunchKernelGGL(atom_gather, dim3(NBLK_G), dim3(256), 0, stream,
                       gr8, gidx, first4, part, out);
}